// Round 3
// baseline (1693.383 us; speedup 1.0000x reference)
//
#include <hip/hip_runtime.h>

typedef unsigned short u16;
typedef unsigned int u32;

#define N_PTS 65536
#define KK 27
#define CIN 4
#define CC 32
#define NWIN 2048
#define CAP 32
#define NH 2
#define HD 16

__device__ __forceinline__ float bf2f(u16 h) { return __uint_as_float(((u32)h) << 16); }
__device__ __forceinline__ u16 f2bf(float f) {
    u32 u = __float_as_uint(f);
    u32 r = (u + 0x7FFFu + ((u >> 16) & 1u)) >> 16;
    return (u16)r;
}

__device__ __forceinline__ float ldv(const float* p) { return *p; }
__device__ __forceinline__ float ldv(const u16* p) { return bf2f(*p); }

// ---- 32-channel row load/store, fp32 or packed bf16 ----
__device__ __forceinline__ void load_row(const float* r, float* o) {
#pragma unroll
    for (int c = 0; c < 32; c += 4) {
        float4 v = *(const float4*)(r + c);
        o[c] = v.x; o[c + 1] = v.y; o[c + 2] = v.z; o[c + 3] = v.w;
    }
}
__device__ __forceinline__ void load_row(const u16* r, float* o) {
#pragma unroll
    for (int q = 0; q < 4; q++) {
        uint4 v = *(const uint4*)(r + q * 8);
        o[q*8+0] = bf2f((u16)(v.x & 0xffffu)); o[q*8+1] = bf2f((u16)(v.x >> 16));
        o[q*8+2] = bf2f((u16)(v.y & 0xffffu)); o[q*8+3] = bf2f((u16)(v.y >> 16));
        o[q*8+4] = bf2f((u16)(v.z & 0xffffu)); o[q*8+5] = bf2f((u16)(v.z >> 16));
        o[q*8+6] = bf2f((u16)(v.w & 0xffffu)); o[q*8+7] = bf2f((u16)(v.w >> 16));
    }
}
__device__ __forceinline__ void store_row(float* r, const float* a) {
#pragma unroll
    for (int c = 0; c < 32; c += 4)
        *(float4*)(r + c) = make_float4(a[c], a[c + 1], a[c + 2], a[c + 3]);
}
__device__ __forceinline__ void store_row(u16* r, const float* a) {
#pragma unroll
    for (int q = 0; q < 4; q++) {
        uint4 v;
        v.x = (u32)f2bf(a[q*8+0]) | ((u32)f2bf(a[q*8+1]) << 16);
        v.y = (u32)f2bf(a[q*8+2]) | ((u32)f2bf(a[q*8+3]) << 16);
        v.z = (u32)f2bf(a[q*8+4]) | ((u32)f2bf(a[q*8+5]) << 16);
        v.w = (u32)f2bf(a[q*8+6]) | ((u32)f2bf(a[q*8+7]) << 16);
        *(uint4*)(r + q * 8) = v;
    }
}

// ---- input float-dtype detection: bf16-packed vs fp32 ----
__global__ void detect_kernel(const u32* __restrict__ w, int* flag) {
    int t = threadIdx.x;
    int cnt = 0;
    for (int i = t; i < 4096; i += 256) {
        u32 e = (w[i] >> 7) & 0xFFu;
        cnt += (e >= 100 && e <= 140) ? 1 : 0;
    }
    __shared__ int red[256];
    red[t] = cnt;
    __syncthreads();
    for (int s = 128; s > 0; s >>= 1) {
        if (t < s) red[t] += red[t + s];
        __syncthreads();
    }
    if (t == 0) flag[0] = (red[0] > 2048) ? 1 : 0;
}

// ---- param prep: (bf16|fp32) -> fp32 into workspace ----
struct Seg { const void* src; int dst; int n; };
struct PrepArgs { Seg s[20]; };

__global__ __launch_bounds__(256) void prep_kernel(PrepArgs a, float* __restrict__ P,
                                                   const int* __restrict__ flag) {
    int seg = blockIdx.y;
    int i = blockIdx.x * 256 + threadIdx.x;
    Seg S = a.s[seg];
    bool isbf = flag[0] != 0;
    if (i < S.n) {
        float v = isbf ? bf2f(((const u16*)S.src)[i]) : ((const float*)S.src)[i];
        P[S.dst + i] = v;
    }
}

// ---- input conv: feats[N,4] -> out[N,32] ----
template <typename TOUT>
__global__ __launch_bounds__(256) void conv_in_kernel(
    const void* __restrict__ feats, const int* __restrict__ flag,
    const int* __restrict__ pairs, const float* __restrict__ W, TOUT* __restrict__ out)
{
    int n = blockIdx.x * 256 + threadIdx.x;
    bool isbf = flag[0] != 0;
    float acc[CC];
#pragma unroll
    for (int d = 0; d < CC; d++) acc[d] = 0.f;

    for (int k = 0; k < KK; k++) {
        int idx = pairs[k * N_PTS + n];
        if (idx >= 0) {
            float r[4];
            if (isbf) {
                uint2 u = *(const uint2*)((const u16*)feats + (long)idx * CIN);
                r[0] = bf2f((u16)(u.x & 0xffffu)); r[1] = bf2f((u16)(u.x >> 16));
                r[2] = bf2f((u16)(u.y & 0xffffu)); r[3] = bf2f((u16)(u.y >> 16));
            } else {
                float4 v = *(const float4*)((const float*)feats + (long)idx * CIN);
                r[0] = v.x; r[1] = v.y; r[2] = v.z; r[3] = v.w;
            }
            const float* wk = W + k * (CIN * CC);
#pragma unroll
            for (int c = 0; c < CIN; c++) {
                float rc = r[c];
#pragma unroll
                for (int d = 0; d < CC; d++)
                    acc[d] = fmaf(rc, wk[c * CC + d], acc[d]);
            }
        }
    }
    store_row(out + (long)n * CC, acc);
}

// ---- 32->32 gather conv, fused BN-ReLU (+residual) ----
template <typename TI, typename TO, bool RESID>
__global__ __launch_bounds__(256) void conv32_kernel(
    const TI* __restrict__ in, const int* __restrict__ pairs,
    const float* __restrict__ W, const float* __restrict__ gb,
    const TO* resid, TO* out)
{
    int n = blockIdx.x * 256 + threadIdx.x;
    float gv[CC], bv[CC];
#pragma unroll
    for (int c = 0; c < CC; c++) { gv[c] = gb[c]; bv[c] = gb[CC + c]; }

    float acc[CC];
#pragma unroll
    for (int d = 0; d < CC; d++) acc[d] = 0.f;

    for (int k = 0; k < KK; k++) {
        int idx = pairs[k * N_PTS + n];
        if (idx >= 0) {
            float row[CC];
            load_row(in + (long)idx * CC, row);
#pragma unroll
            for (int c = 0; c < CC; c++)
                row[c] = fmaxf(fmaf(row[c], gv[c], bv[c]), 0.f);
            const float* wk = W + k * (CC * CC);
#pragma unroll
            for (int c = 0; c < CC; c++) {
                float rc = row[c];
#pragma unroll
                for (int d = 0; d < CC; d++)
                    acc[d] = fmaf(rc, wk[c * CC + d], acc[d]);
            }
        }
    }
    if (RESID) {
        float rr[CC];
        load_row(resid + (long)n * CC, rr);
#pragma unroll
        for (int c = 0; c < CC; c++) acc[c] += rr[c];
    }
    store_row(out + (long)n * CC, acc);
}

// ---- fused windowed attention; output fp32 (S-B bet) ----
template <typename TX>
__global__ __launch_bounds__(256) void attn_kernel(
    const TX* __restrict__ x, const int* __restrict__ win_idx,
    const int* __restrict__ rel_idx,
    const float* __restrict__ wqkv, const float* __restrict__ bqkv,
    const float* __restrict__ wproj, const float* __restrict__ bproj,
    const float* __restrict__ tq, const float* __restrict__ tk, const float* __restrict__ tv,
    float* __restrict__ out)
{
    __shared__ float xw[CAP][CC + 1];
    __shared__ float qs[CAP][CC + 1];
    __shared__ float ks_[CAP][CC + 1];
    __shared__ float vs[CAP][CC + 1];
    __shared__ float sc[NH][CAP][CAP];
    __shared__ float ot[CAP][CC];
    __shared__ int ridx[CAP * CAP];
    __shared__ int widx[CAP];

    int w = blockIdx.x, t = threadIdx.x;
    if (t < CAP) widx[t] = win_idx[w * CAP + t];
    __syncthreads();

    for (int e = t; e < CAP * CC; e += 256) {
        int i = e >> 5, c = e & 31;
        xw[i][c] = ldv(x + (long)widx[i] * CC + c);
        ridx[e] = rel_idx[(long)w * CAP * CAP + e];
    }
    __syncthreads();

    // qkv projection
    for (int e = t; e < CAP * 96; e += 256) {
        int i = e / 96, tt = e % 96;
        float s = bqkv[tt];
#pragma unroll
        for (int c = 0; c < CC; c++) s = fmaf(xw[i][c], wqkv[c * 96 + tt], s);
        int trip = tt >> 5, hd = tt & 31;
        if (trip == 0)      qs[i][hd] = s * 0.25f;   // HD^-0.5
        else if (trip == 1) ks_[i][hd] = s;
        else                vs[i][hd] = s;
    }
    __syncthreads();

    // scores + relative bias
    for (int e = t; e < NH * CAP * CAP; e += 256) {
        int h = e >> 10, i = (e >> 5) & 31, j = e & 31;
        int r = ridx[i * CAP + j];
        const float* tqr = tq + r * CC + h * HD;
        const float* tkr = tk + r * CC + h * HD;
        float s = 0.f;
#pragma unroll
        for (int d = 0; d < HD; d++) {
            float qv = qs[i][h * HD + d], kv = ks_[j][h * HD + d];
            s = fmaf(qv, kv, s);
            s = fmaf(qv, tqr[d], s);
            s = fmaf(kv, tkr[d], s);
        }
        sc[h][i][j] = s;
    }
    __syncthreads();

    // softmax over j
    if (t < NH * CAP) {
        int h = t >> 5, i = t & 31;
        float m = -1e30f;
#pragma unroll
        for (int j = 0; j < CAP; j++) m = fmaxf(m, sc[h][i][j]);
        float p[CAP];
        float sum = 0.f;
#pragma unroll
        for (int j = 0; j < CAP; j++) { p[j] = __expf(sc[h][i][j] - m); sum += p[j]; }
        float inv = 1.f / sum;
#pragma unroll
        for (int j = 0; j < CAP; j++) sc[h][i][j] = p[j] * inv;
    }
    __syncthreads();

    // out = attn @ (v + tv[rel])
    for (int e = t; e < CAP * CC; e += 256) {
        int i = e >> 5, hd = e & 31, h = hd >> 4;
        float o = 0.f;
        for (int j = 0; j < CAP; j++) {
            float pv = sc[h][i][j];
            float tvv = tv[(long)ridx[i * CAP + j] * CC + hd];
            o = fmaf(pv, vs[j][hd] + tvv, o);
        }
        ot[i][hd] = o;
    }
    __syncthreads();

    // proj + residual scatter (win_idx is a permutation), fp32 out
    for (int e = t; e < CAP * CC; e += 256) {
        int i = e >> 5, c = e & 31;
        float s = bproj[c];
#pragma unroll
        for (int e2 = 0; e2 < CC; e2++) s = fmaf(ot[i][e2], wproj[e2 * CC + c], s);
        int n = widx[i];
        out[(long)n * CC + c] = xw[i][c] + s;
    }
}

// ---- workspace layout (float offsets for params) ----
#define OFF_WIN   0
#define OFF_W1A   3456
#define OFF_W2A   31104
#define OFF_W1B   58752
#define OFF_W2B   86400
#define OFF_GB    114048
#define OFF_WQKV  114304
#define OFF_BQKV  117376
#define OFF_WPROJ 117472
#define OFF_BPROJ 118496
#define OFF_TQ    118528
#define OFF_TK    123136
#define OFF_TV    127744
#define P_FLOATS  132352

template <typename TA, typename TB>
static void run_chain(const void* feats, const int* flag, const int* pairs,
                      const int* win_idx, const int* rel_idx, const float* P,
                      TA* A, TB* B, float* outp, hipStream_t stream)
{
    conv_in_kernel<TA><<<N_PTS / 256, 256, 0, stream>>>(feats, flag, pairs, P + OFF_WIN, A);
    conv32_kernel<TA, TB, false><<<N_PTS / 256, 256, 0, stream>>>(A, pairs, P + OFF_W1A, P + OFF_GB + 0,   (const TB*)nullptr, B);
    conv32_kernel<TB, TA, true ><<<N_PTS / 256, 256, 0, stream>>>(B, pairs, P + OFF_W2A, P + OFF_GB + 64,  (const TA*)A,       A);
    conv32_kernel<TA, TB, false><<<N_PTS / 256, 256, 0, stream>>>(A, pairs, P + OFF_W1B, P + OFF_GB + 128, (const TB*)nullptr, B);
    conv32_kernel<TB, TA, true ><<<N_PTS / 256, 256, 0, stream>>>(B, pairs, P + OFF_W2B, P + OFF_GB + 192, (const TA*)A,       A);
    attn_kernel<TA><<<NWIN, 256, 0, stream>>>(A, win_idx, rel_idx,
                                              P + OFF_WQKV, P + OFF_BQKV, P + OFF_WPROJ, P + OFF_BPROJ,
                                              P + OFF_TQ, P + OFF_TK, P + OFF_TV, outp);
}

extern "C" void kernel_launch(void* const* d_in, const int* in_sizes, int n_in,
                              void* d_out, int out_size, void* d_ws, size_t ws_size,
                              hipStream_t stream) {
    const void* feats  = d_in[0];
    const int* pairs   = (const int*)d_in[1];
    const int* win_idx = (const int*)d_in[2];
    const int* rel_idx = (const int*)d_in[3];

    char* wsb = (char*)d_ws;
    float* P  = (float*)wsb;
    int* flag = (int*)(wsb + (size_t)P_FLOATS * 4);     // 529408
    const size_t offA = 529920;                          // 16B-aligned scratch start

    detect_kernel<<<1, 256, 0, stream>>>((const u32*)feats, flag);

    PrepArgs pa;
    int si = 0;
    auto add = [&](int ii, int off, int n) {
        pa.s[si].src = d_in[ii]; pa.s[si].dst = off; pa.s[si].n = n; si++;
    };
    add(4,  OFF_WIN,   3456);
    add(7,  OFF_W1A,   27648);
    add(10, OFF_W2A,   27648);
    add(13, OFF_W1B,   27648);
    add(16, OFF_W2B,   27648);
    add(5,  OFF_GB + 0,   32);
    add(6,  OFF_GB + 32,  32);
    add(8,  OFF_GB + 64,  32);
    add(9,  OFF_GB + 96,  32);
    add(11, OFF_GB + 128, 32);
    add(12, OFF_GB + 160, 32);
    add(14, OFF_GB + 192, 32);
    add(15, OFF_GB + 224, 32);
    add(17, OFF_WQKV,  3072);
    add(18, OFF_BQKV,  96);
    add(19, OFF_WPROJ, 1024);
    add(20, OFF_BPROJ, 32);
    add(21, OFF_TQ,    4608);
    add(22, OFF_TK,    4608);
    add(23, OFF_TV,    4608);
    prep_kernel<<<dim3(108, 20), 256, 0, stream>>>(pa, P, flag);

    float* outp = (float*)d_out;
    const size_t bufF32 = (size_t)N_PTS * CC * 4;   // 8 MB

    if (ws_size >= offA + 2 * bufF32 + 1024) {
        // tier 1: both intermediates fp32 in ws
        float* A = (float*)(wsb + offA);
        float* B = A + (size_t)N_PTS * CC;
        run_chain<float, float>(feats, flag, pairs, win_idx, rel_idx, P, A, B, outp, stream);
    } else if (ws_size >= offA + bufF32 + 1024) {
        // tier 2: A fp32 in ws, B bf16 in first 4MB of d_out (dead before attn writes)
        float* A = (float*)(wsb + offA);
        u16* B = (u16*)d_out;
        run_chain<float, u16>(feats, flag, pairs, win_idx, rel_idx, P, A, B, outp, stream);
    } else {
        // tier 3: A bf16 in ws, B bf16 in first 4MB of d_out
        u16* A = (u16*)(wsb + offA);
        u16* B = (u16*)d_out;
        run_chain<u16, u16>(feats, flag, pairs, win_idx, rel_idx, P, A, B, outp, stream);
    }
}

// Round 4
// 203.681 us; speedup vs baseline: 8.3139x; 8.3139x over previous
//
#include <hip/hip_runtime.h>

typedef unsigned short u16;
typedef unsigned int u32;

#define N_PTS 65536
#define KK 27
#define CIN 4
#define CC 32
#define NWIN 2048
#define CAP 32
#define NH 2
#define HD 16

typedef short s16x8 __attribute__((ext_vector_type(8)));
typedef float f32x4 __attribute__((ext_vector_type(4)));

__device__ __forceinline__ float bf2f(u16 h) { return __uint_as_float(((u32)h) << 16); }
__device__ __forceinline__ u16 f2bf(float f) {
    u32 u = __float_as_uint(f);
    u32 r = (u + 0x7FFFu + ((u >> 16) & 1u)) >> 16;
    return (u16)r;
}
__device__ __forceinline__ float ldv(const float* p) { return *p; }

// ---- input float-dtype detection (kept for robustness) ----
__global__ void detect_kernel(const u32* __restrict__ w, int* flag) {
    int t = threadIdx.x;
    int cnt = 0;
    for (int i = t; i < 4096; i += 256) {
        u32 e = (w[i] >> 7) & 0xFFu;
        cnt += (e >= 100 && e <= 140) ? 1 : 0;
    }
    __shared__ int red[256];
    red[t] = cnt;
    __syncthreads();
    for (int s = 128; s > 0; s >>= 1) {
        if (t < s) red[t] += red[t + s];
        __syncthreads();
    }
    if (t == 0) flag[0] = (red[0] > 2048) ? 1 : 0;
}

// ---- prep1: params (bf16|fp32) -> fp32 P ----
struct Seg { const void* src; int dst; int n; };
struct PrepArgs { Seg s[20]; };

__global__ __launch_bounds__(256) void prep_kernel(PrepArgs a, float* __restrict__ P,
                                                   const int* __restrict__ flag) {
    int seg = blockIdx.y;
    int i = blockIdx.x * 256 + threadIdx.x;
    Seg S = a.s[seg];
    bool isbf = flag[0] != 0;
    if (i < S.n) {
        float v = isbf ? bf2f(((const u16*)S.src)[i]) : ((const float*)S.src)[i];
        P[S.dst + i] = v;
    }
}

// ---- workspace float offsets for P ----
#define OFF_WIN   0
#define OFF_W1A   3456
#define OFF_W2A   31104
#define OFF_W1B   58752
#define OFF_W2B   86400
#define OFF_GB    114048
#define OFF_WQKV  114304
#define OFF_BQKV  117376
#define OFF_WPROJ 117472
#define OFF_BPROJ 118496
#define OFF_TQ    118528
#define OFF_TK    123136
#define OFF_TV    127744
#define P_FLOATS  132352

// ---- prep2: feats->bf16, weights -> B-fragment-ordered bf16 ----
// W' layout per conv: [k][dt][lane 0..63][e 0..7] bf16; elem = w[k][(l>>4)*8+e][dt*16+(l&15)]
__global__ __launch_bounds__(256) void prep2_kernel(
    const void* __restrict__ feats, const int* __restrict__ flag,
    const float* __restrict__ P,
    u16* __restrict__ featsbf,
    u16* __restrict__ WpA1, u16* __restrict__ WpA2,
    u16* __restrict__ WpB1, u16* __restrict__ WpB2,
    u16* __restrict__ WpIN)
{
    int seg = blockIdx.y;
    int i = blockIdx.x * 256 + threadIdx.x;
    if (seg == 0) {
        if (i < N_PTS * CIN) {
            bool isbf = flag[0] != 0;
            featsbf[i] = isbf ? ((const u16*)feats)[i] : f2bf(((const float*)feats)[i]);
        }
        return;
    }
    if (seg <= 4) {
        if (i < 27648) {
            int e = i & 7, l = (i >> 3) & 63, dt = (i >> 9) & 1, k = i >> 10;
            int woff = (seg == 1 ? OFF_W1A : seg == 2 ? OFF_W2A : seg == 3 ? OFF_W1B : OFF_W2B);
            u16* dst = (seg == 1 ? WpA1 : seg == 2 ? WpA2 : seg == 3 ? WpB1 : WpB2);
            dst[i] = f2bf(P[woff + k * 1024 + ((l >> 4) * 8 + e) * 32 + dt * 16 + (l & 15)]);
        }
        return;
    }
    if (i < 4096) {
        int e = i & 7, l = (i >> 3) & 63, dt = (i >> 9) & 1, kk = i >> 10;
        int g = kk * 32 + (l >> 4) * 8 + e;
        int tp = g >> 2, c = g & 3;
        WpIN[i] = (tp < KK) ? f2bf(P[OFF_WIN + tp * 128 + c * 32 + dt * 16 + (l & 15)]) : (u16)0;
    }
}

// ---- MFMA input conv: feats[N,4]bf16, taps packed 4-wide into K=128 ----
__global__ __launch_bounds__(256) void convin_mfma(
    const u16* __restrict__ fb, const int* __restrict__ pairs,
    const u16* __restrict__ Wp, const float* __restrict__ gb,
    float* __restrict__ xbuf, u16* __restrict__ act_out)
{
    int t = threadIdx.x;
    int wv = t >> 6, l = t & 63;
    int lr = l & 15, lg = l >> 4;
    int p0 = (blockIdx.x * 4 + wv) * 16;
    int rowaddr = p0 + lr;

    f32x4 acc0 = {0.f, 0.f, 0.f, 0.f}, acc1 = {0.f, 0.f, 0.f, 0.f};
#pragma unroll
    for (int kk = 0; kk < 4; kk++) {
        int t0 = kk * 8 + lg * 2;
        int ta = t0 < 26 ? t0 : 26;
        int tb = (t0 + 1) < 26 ? (t0 + 1) : 26;
        int ia = pairs[ta * N_PTS + rowaddr];
        int ib = pairs[tb * N_PTS + rowaddr];
        u32 ma = (t0 < KK && ia >= 0) ? 0xFFFFFFFFu : 0u;
        u32 mb = (t0 + 1 < KK && ib >= 0) ? 0xFFFFFFFFu : 0u;
        uint2 qa = *(const uint2*)(fb + (long)(ia < 0 ? 0 : ia) * CIN);
        uint2 qb = *(const uint2*)(fb + (long)(ib < 0 ? 0 : ib) * CIN);
        union { uint4 q; s16x8 v; } a;
        a.q = make_uint4(qa.x & ma, qa.y & ma, qb.x & mb, qb.y & mb);
        const s16x8* wb = (const s16x8*)Wp + kk * 128 + l;
        s16x8 b0 = wb[0];
        s16x8 b1 = wb[64];
        acc0 = __builtin_amdgcn_mfma_f32_16x16x32_bf16(a.v, b0, acc0, 0, 0, 0);
        acc1 = __builtin_amdgcn_mfma_f32_16x16x32_bf16(a.v, b1, acc1, 0, 0, 0);
    }
    float g0 = gb[lr], b0v = gb[32 + lr], g1 = gb[16 + lr], b1v = gb[48 + lr];
#pragma unroll
    for (int r = 0; r < 4; r++) {
        int row = p0 + lg * 4 + r;
        long o0 = (long)row * 32 + lr, o1 = o0 + 16;
        float v0 = acc0[r], v1 = acc1[r];
        xbuf[o0] = v0; xbuf[o1] = v1;
        act_out[o0] = f2bf(fmaxf(fmaf(v0, g0, b0v), 0.f));
        act_out[o1] = f2bf(fmaxf(fmaf(v1, g1, b1v), 0.f));
    }
}

// ---- MFMA 32->32 gather conv; M: bit0 READ_X, bit1 WRITE_X, bit2 WRITE_ACT ----
template <int M>
__global__ __launch_bounds__(256) void conv32_mfma(
    const u16* __restrict__ act_in, const int* __restrict__ pairs,
    const u16* __restrict__ Wp, const float* __restrict__ gb,
    float* __restrict__ xbuf, u16* __restrict__ act_out)
{
    int t = threadIdx.x;
    int wv = t >> 6, l = t & 63;
    int lr = l & 15, lg = l >> 4;
    int p0 = (blockIdx.x * 4 + wv) * 16;
    int rowaddr = p0 + lr;

    f32x4 acc0 = {0.f, 0.f, 0.f, 0.f}, acc1 = {0.f, 0.f, 0.f, 0.f};
    for (int k = 0; k < KK; k++) {
        int idx = pairs[k * N_PTS + rowaddr];
        const s16x8* wb = (const s16x8*)Wp + k * 128 + l;
        s16x8 b0 = wb[0];
        s16x8 b1 = wb[64];
        int ic = idx < 0 ? 0 : idx;
        uint4 q = *(const uint4*)(act_in + (long)ic * CC + lg * 8);
        u32 msk = idx >= 0 ? 0xFFFFFFFFu : 0u;
        q.x &= msk; q.y &= msk; q.z &= msk; q.w &= msk;
        union { uint4 q; s16x8 v; } a;
        a.q = q;
        acc0 = __builtin_amdgcn_mfma_f32_16x16x32_bf16(a.v, b0, acc0, 0, 0, 0);
        acc1 = __builtin_amdgcn_mfma_f32_16x16x32_bf16(a.v, b1, acc1, 0, 0, 0);
    }
    float g0 = 0.f, b0v = 0.f, g1 = 0.f, b1v = 0.f;
    if (M & 4) { g0 = gb[lr]; b0v = gb[32 + lr]; g1 = gb[16 + lr]; b1v = gb[48 + lr]; }
#pragma unroll
    for (int r = 0; r < 4; r++) {
        int row = p0 + lg * 4 + r;
        long o0 = (long)row * 32 + lr, o1 = o0 + 16;
        float v0 = acc0[r], v1 = acc1[r];
        if (M & 1) { v0 += xbuf[o0]; v1 += xbuf[o1]; }
        if (M & 2) { xbuf[o0] = v0; xbuf[o1] = v1; }
        if (M & 4) {
            act_out[o0] = f2bf(fmaxf(fmaf(v0, g0, b0v), 0.f));
            act_out[o1] = f2bf(fmaxf(fmaf(v1, g1, b1v), 0.f));
        }
    }
}

// ---- fused windowed attention (fp32, in-place on d_out) ----
__global__ __launch_bounds__(256) void attn_kernel(
    const float* __restrict__ x, const int* __restrict__ win_idx,
    const int* __restrict__ rel_idx,
    const float* __restrict__ wqkv, const float* __restrict__ bqkv,
    const float* __restrict__ wproj, const float* __restrict__ bproj,
    const float* __restrict__ tq, const float* __restrict__ tk, const float* __restrict__ tv,
    float* __restrict__ out)
{
    __shared__ float xw[CAP][CC + 1];
    __shared__ float qs[CAP][CC + 1];
    __shared__ float ks_[CAP][CC + 1];
    __shared__ float vs[CAP][CC + 1];
    __shared__ float sc[NH][CAP][CAP];
    __shared__ float ot[CAP][CC];
    __shared__ int ridx[CAP * CAP];
    __shared__ int widx[CAP];

    int w = blockIdx.x, t = threadIdx.x;
    if (t < CAP) widx[t] = win_idx[w * CAP + t];
    __syncthreads();

    for (int e = t; e < CAP * CC; e += 256) {
        int i = e >> 5, c = e & 31;
        xw[i][c] = ldv(x + (long)widx[i] * CC + c);
        ridx[e] = rel_idx[(long)w * CAP * CAP + e];
    }
    __syncthreads();

    for (int e = t; e < CAP * 96; e += 256) {
        int i = e / 96, tt = e % 96;
        float s = bqkv[tt];
#pragma unroll
        for (int c = 0; c < CC; c++) s = fmaf(xw[i][c], wqkv[c * 96 + tt], s);
        int trip = tt >> 5, hd = tt & 31;
        if (trip == 0)      qs[i][hd] = s * 0.25f;
        else if (trip == 1) ks_[i][hd] = s;
        else                vs[i][hd] = s;
    }
    __syncthreads();

    for (int e = t; e < NH * CAP * CAP; e += 256) {
        int h = e >> 10, i = (e >> 5) & 31, j = e & 31;
        int r = ridx[i * CAP + j];
        const float* tqr = tq + r * CC + h * HD;
        const float* tkr = tk + r * CC + h * HD;
        float s = 0.f;
#pragma unroll
        for (int d = 0; d < HD; d++) {
            float qv = qs[i][h * HD + d], kv = ks_[j][h * HD + d];
            s = fmaf(qv, kv, s);
            s = fmaf(qv, tqr[d], s);
            s = fmaf(kv, tkr[d], s);
        }
        sc[h][i][j] = s;
    }
    __syncthreads();

    if (t < NH * CAP) {
        int h = t >> 5, i = t & 31;
        float m = -1e30f;
#pragma unroll
        for (int j = 0; j < CAP; j++) m = fmaxf(m, sc[h][i][j]);
        float p[CAP];
        float sum = 0.f;
#pragma unroll
        for (int j = 0; j < CAP; j++) { p[j] = __expf(sc[h][i][j] - m); sum += p[j]; }
        float inv = 1.f / sum;
#pragma unroll
        for (int j = 0; j < CAP; j++) sc[h][i][j] = p[j] * inv;
    }
    __syncthreads();

    for (int e = t; e < CAP * CC; e += 256) {
        int i = e >> 5, hd = e & 31, h = hd >> 4;
        float o = 0.f;
        for (int j = 0; j < CAP; j++) {
            float pv = sc[h][i][j];
            float tvv = tv[(long)ridx[i * CAP + j] * CC + hd];
            o = fmaf(pv, vs[j][hd] + tvv, o);
        }
        ot[i][hd] = o;
    }
    __syncthreads();

    for (int e = t; e < CAP * CC; e += 256) {
        int i = e >> 5, c = e & 31;
        float s = bproj[c];
#pragma unroll
        for (int e2 = 0; e2 < CC; e2++) s = fmaf(ot[i][e2], wproj[e2 * CC + c], s);
        int n = widx[i];
        out[(long)n * CC + c] = xw[i][c] + s;
    }
}

// ---- ws byte offsets ----
#define B_FLAG   529408    // after P (132352*4)
#define B_ACTA   529920
#define B_ACTB   4724224
#define B_FEATS  8918528
#define B_WA1    9442816
#define B_WA2    9498112
#define B_WB1    9553408
#define B_WB2    9608704
#define B_WIN    9664000

extern "C" void kernel_launch(void* const* d_in, const int* in_sizes, int n_in,
                              void* d_out, int out_size, void* d_ws, size_t ws_size,
                              hipStream_t stream) {
    const void* feats  = d_in[0];
    const int* pairs   = (const int*)d_in[1];
    const int* win_idx = (const int*)d_in[2];
    const int* rel_idx = (const int*)d_in[3];

    char* wsb = (char*)d_ws;
    float* P  = (float*)wsb;
    int* flag = (int*)(wsb + B_FLAG);
    u16* actA = (u16*)(wsb + B_ACTA);
    u16* actB = (u16*)(wsb + B_ACTB);
    u16* fbf  = (u16*)(wsb + B_FEATS);
    u16* WpA1 = (u16*)(wsb + B_WA1);
    u16* WpA2 = (u16*)(wsb + B_WA2);
    u16* WpB1 = (u16*)(wsb + B_WB1);
    u16* WpB2 = (u16*)(wsb + B_WB2);
    u16* WpIN = (u16*)(wsb + B_WIN);
    float* X  = (float*)d_out;

    detect_kernel<<<1, 256, 0, stream>>>((const u32*)feats, flag);

    PrepArgs pa;
    int si = 0;
    auto add = [&](int ii, int off, int n) {
        pa.s[si].src = d_in[ii]; pa.s[si].dst = off; pa.s[si].n = n; si++;
    };
    add(4,  OFF_WIN,   3456);
    add(7,  OFF_W1A,   27648);
    add(10, OFF_W2A,   27648);
    add(13, OFF_W1B,   27648);
    add(16, OFF_W2B,   27648);
    add(5,  OFF_GB + 0,   32);
    add(6,  OFF_GB + 32,  32);
    add(8,  OFF_GB + 64,  32);
    add(9,  OFF_GB + 96,  32);
    add(11, OFF_GB + 128, 32);
    add(12, OFF_GB + 160, 32);
    add(14, OFF_GB + 192, 32);
    add(15, OFF_GB + 224, 32);
    add(17, OFF_WQKV,  3072);
    add(18, OFF_BQKV,  96);
    add(19, OFF_WPROJ, 1024);
    add(20, OFF_BPROJ, 32);
    add(21, OFF_TQ,    4608);
    add(22, OFF_TK,    4608);
    add(23, OFF_TV,    4608);
    prep_kernel<<<dim3(108, 20), 256, 0, stream>>>(pa, P, flag);

    prep2_kernel<<<dim3(1024, 6), 256, 0, stream>>>(feats, flag, P, fbf,
                                                    WpA1, WpA2, WpB1, WpB2, WpIN);

    // x-chain lives in d_out; act ping-pongs in ws
    convin_mfma<<<1024, 256, 0, stream>>>(fbf, pairs, WpIN, P + OFF_GB + 0, X, actA);
    conv32_mfma<4><<<1024, 256, 0, stream>>>(actA, pairs, WpA1, P + OFF_GB + 64,  X, actB);
    conv32_mfma<7><<<1024, 256, 0, stream>>>(actB, pairs, WpA2, P + OFF_GB + 128, X, actA);
    conv32_mfma<4><<<1024, 256, 0, stream>>>(actA, pairs, WpB1, P + OFF_GB + 192, X, actB);
    conv32_mfma<3><<<1024, 256, 0, stream>>>(actB, pairs, WpB2, P, X, actA);

    attn_kernel<<<NWIN, 256, 0, stream>>>(X, win_idx, rel_idx,
                                          P + OFF_WQKV, P + OFF_BQKV, P + OFF_WPROJ, P + OFF_BPROJ,
                                          P + OFF_TQ, P + OFF_TK, P + OFF_TV, X);
}

// Round 5
// 175.730 us; speedup vs baseline: 9.6363x; 1.1591x over previous
//
#include <hip/hip_runtime.h>

typedef unsigned short u16;
typedef unsigned int u32;

#define N_PTS 65536
#define KK 27
#define CIN 4
#define CC 32
#define NWIN 2048
#define CAP 32
#define NH 2
#define HD 16

typedef short s16x8 __attribute__((ext_vector_type(8)));
typedef float f32x4 __attribute__((ext_vector_type(4)));

__device__ __forceinline__ float bf2f(u16 h) { return __uint_as_float(((u32)h) << 16); }
__device__ __forceinline__ u16 f2bf(float f) {
    u32 u = __float_as_uint(f);
    u32 r = (u + 0x7FFFu + ((u >> 16) & 1u)) >> 16;
    return (u16)r;
}

// ---- input float-dtype detection (kept for robustness) ----
__global__ void detect_kernel(const u32* __restrict__ w, int* flag) {
    int t = threadIdx.x;
    int cnt = 0;
    for (int i = t; i < 4096; i += 256) {
        u32 e = (w[i] >> 7) & 0xFFu;
        cnt += (e >= 100 && e <= 140) ? 1 : 0;
    }
    __shared__ int red[256];
    red[t] = cnt;
    __syncthreads();
    for (int s = 128; s > 0; s >>= 1) {
        if (t < s) red[t] += red[t + s];
        __syncthreads();
    }
    if (t == 0) flag[0] = (red[0] > 2048) ? 1 : 0;
}

// ---- prep1: params (bf16|fp32) -> fp32 P ----
struct Seg { const void* src; int dst; int n; };
struct PrepArgs { Seg s[20]; };

__global__ __launch_bounds__(256) void prep_kernel(PrepArgs a, float* __restrict__ P,
                                                   const int* __restrict__ flag) {
    int seg = blockIdx.y;
    int i = blockIdx.x * 256 + threadIdx.x;
    Seg S = a.s[seg];
    bool isbf = flag[0] != 0;
    if (i < S.n) {
        float v = isbf ? bf2f(((const u16*)S.src)[i]) : ((const float*)S.src)[i];
        P[S.dst + i] = v;
    }
}

// ---- workspace float offsets for P ----
#define OFF_WIN   0
#define OFF_W1A   3456
#define OFF_W2A   31104
#define OFF_W1B   58752
#define OFF_W2B   86400
#define OFF_GB    114048
#define OFF_WQKV  114304
#define OFF_BQKV  117376
#define OFF_WPROJ 117472
#define OFF_BPROJ 118496
#define OFF_TQ    118528
#define OFF_TK    123136
#define OFF_TV    127744
#define P_FLOATS  132352

// ---- prep2: feats->bf16, conv weights -> B-frag order, attn tables ----
__global__ __launch_bounds__(256) void prep2_kernel(
    const void* __restrict__ feats, const int* __restrict__ flag,
    const float* __restrict__ P,
    u16* __restrict__ featsbf,
    u16* __restrict__ WpA1, u16* __restrict__ WpA2,
    u16* __restrict__ WpB1, u16* __restrict__ WpB2,
    u16* __restrict__ WpIN,
    float* __restrict__ wqkvT, float* __restrict__ wprojT,
    u16* __restrict__ tqb, u16* __restrict__ tkb, u16* __restrict__ tvb)
{
    int seg = blockIdx.y;
    int i = blockIdx.x * 256 + threadIdx.x;
    if (seg == 0) {
        if (i < N_PTS * CIN) {
            bool isbf = flag[0] != 0;
            featsbf[i] = isbf ? ((const u16*)feats)[i] : f2bf(((const float*)feats)[i]);
        }
        return;
    }
    if (seg <= 4) {
        if (i < 27648) {
            int e = i & 7, l = (i >> 3) & 63, dt = (i >> 9) & 1, k = i >> 10;
            int woff = (seg == 1 ? OFF_W1A : seg == 2 ? OFF_W2A : seg == 3 ? OFF_W1B : OFF_W2B);
            u16* dst = (seg == 1 ? WpA1 : seg == 2 ? WpA2 : seg == 3 ? WpB1 : WpB2);
            dst[i] = f2bf(P[woff + k * 1024 + ((l >> 4) * 8 + e) * 32 + dt * 16 + (l & 15)]);
        }
        return;
    }
    if (seg == 5) {
        if (i < 4096) {
            int e = i & 7, l = (i >> 3) & 63, dt = (i >> 9) & 1, kk = i >> 10;
            int g = kk * 32 + (l >> 4) * 8 + e;
            int tp = g >> 2, c = g & 3;
            WpIN[i] = (tp < KK) ? f2bf(P[OFF_WIN + tp * 128 + c * 32 + dt * 16 + (l & 15)]) : (u16)0;
        }
        return;
    }
    if (seg == 6) {
        if (i < 3072) {
            int tt = i >> 5, c = i & 31;
            wqkvT[i] = P[OFF_WQKV + c * 96 + tt];
        } else if (i < 4096) {
            int o = i - 3072;
            int co = o >> 5, ci = o & 31;
            wprojT[o] = P[OFF_WPROJ + ci * 32 + co];
        }
        return;
    }
    // seg 7: bf16 rel tables
    if (i < 4608)            tqb[i] = f2bf(P[OFF_TQ + i]);
    else if (i < 9216)       tkb[i - 4608] = f2bf(P[OFF_TK + (i - 4608)]);
    else if (i < 13824)      tvb[i - 9216] = f2bf(P[OFF_TV + (i - 9216)]);
}

// ---- MFMA input conv: feats[N,4]bf16, taps packed 4-wide into K=128 ----
__global__ __launch_bounds__(256) void convin_mfma(
    const u16* __restrict__ fb, const int* __restrict__ pairs,
    const u16* __restrict__ Wp, const float* __restrict__ gb,
    float* __restrict__ xbuf, u16* __restrict__ act_out)
{
    int t = threadIdx.x;
    int wv = t >> 6, l = t & 63;
    int lr = l & 15, lg = l >> 4;
    int p0 = (blockIdx.x * 4 + wv) * 16;
    int rowaddr = p0 + lr;

    f32x4 acc0 = {0.f, 0.f, 0.f, 0.f}, acc1 = {0.f, 0.f, 0.f, 0.f};
#pragma unroll
    for (int kk = 0; kk < 4; kk++) {
        int t0 = kk * 8 + lg * 2;
        int ta = t0 < 26 ? t0 : 26;
        int tb = (t0 + 1) < 26 ? (t0 + 1) : 26;
        int ia = pairs[ta * N_PTS + rowaddr];
        int ib = pairs[tb * N_PTS + rowaddr];
        u32 ma = (t0 < KK && ia >= 0) ? 0xFFFFFFFFu : 0u;
        u32 mb = (t0 + 1 < KK && ib >= 0) ? 0xFFFFFFFFu : 0u;
        uint2 qa = *(const uint2*)(fb + (long)(ia < 0 ? 0 : ia) * CIN);
        uint2 qb = *(const uint2*)(fb + (long)(ib < 0 ? 0 : ib) * CIN);
        union { uint4 q; s16x8 v; } a;
        a.q = make_uint4(qa.x & ma, qa.y & ma, qb.x & mb, qb.y & mb);
        const s16x8* wb = (const s16x8*)Wp + kk * 128 + l;
        s16x8 b0 = wb[0];
        s16x8 b1 = wb[64];
        acc0 = __builtin_amdgcn_mfma_f32_16x16x32_bf16(a.v, b0, acc0, 0, 0, 0);
        acc1 = __builtin_amdgcn_mfma_f32_16x16x32_bf16(a.v, b1, acc1, 0, 0, 0);
    }
    float g0 = gb[lr], b0v = gb[32 + lr], g1 = gb[16 + lr], b1v = gb[48 + lr];
#pragma unroll
    for (int r = 0; r < 4; r++) {
        int row = p0 + lg * 4 + r;
        long o0 = (long)row * 32 + lr, o1 = o0 + 16;
        float v0 = acc0[r], v1 = acc1[r];
        xbuf[o0] = v0; xbuf[o1] = v1;
        act_out[o0] = f2bf(fmaxf(fmaf(v0, g0, b0v), 0.f));
        act_out[o1] = f2bf(fmaxf(fmaf(v1, g1, b1v), 0.f));
    }
}

// ---- MFMA 32->32 gather conv; M: bit0 READ_X, bit1 WRITE_X, bit2 WRITE_ACT ----
template <int M>
__global__ __launch_bounds__(256) void conv32_mfma(
    const u16* __restrict__ act_in, const int* __restrict__ pairs,
    const u16* __restrict__ Wp, const float* __restrict__ gb,
    float* __restrict__ xbuf, u16* __restrict__ act_out)
{
    int t = threadIdx.x;
    int wv = t >> 6, l = t & 63;
    int lr = l & 15, lg = l >> 4;
    int p0 = (blockIdx.x * 4 + wv) * 16;
    int rowaddr = p0 + lr;

    f32x4 acc0 = {0.f, 0.f, 0.f, 0.f}, acc1 = {0.f, 0.f, 0.f, 0.f};
    for (int k = 0; k < KK; k++) {
        int idx = pairs[k * N_PTS + rowaddr];
        const s16x8* wb = (const s16x8*)Wp + k * 128 + l;
        s16x8 b0 = wb[0];
        s16x8 b1 = wb[64];
        int ic = idx < 0 ? 0 : idx;
        uint4 q = *(const uint4*)(act_in + (long)ic * CC + lg * 8);
        u32 msk = idx >= 0 ? 0xFFFFFFFFu : 0u;
        q.x &= msk; q.y &= msk; q.z &= msk; q.w &= msk;
        union { uint4 q; s16x8 v; } a;
        a.q = q;
        acc0 = __builtin_amdgcn_mfma_f32_16x16x32_bf16(a.v, b0, acc0, 0, 0, 0);
        acc1 = __builtin_amdgcn_mfma_f32_16x16x32_bf16(a.v, b1, acc1, 0, 0, 0);
    }
    float g0 = 0.f, b0v = 0.f, g1 = 0.f, b1v = 0.f;
    if (M & 4) { g0 = gb[lr]; b0v = gb[32 + lr]; g1 = gb[16 + lr]; b1v = gb[48 + lr]; }
#pragma unroll
    for (int r = 0; r < 4; r++) {
        int row = p0 + lg * 4 + r;
        long o0 = (long)row * 32 + lr, o1 = o0 + 16;
        float v0 = acc0[r], v1 = acc1[r];
        if (M & 1) { v0 += xbuf[o0]; v1 += xbuf[o1]; }
        if (M & 2) { xbuf[o0] = v0; xbuf[o1] = v1; }
        if (M & 4) {
            act_out[o0] = f2bf(fmaxf(fmaf(v0, g0, b0v), 0.f));
            act_out[o1] = f2bf(fmaxf(fmaf(v1, g1, b1v), 0.f));
        }
    }
}

// ---- fused windowed attention v2 ----
__global__ __launch_bounds__(256) void attn2_kernel(
    const float* __restrict__ x, const int* __restrict__ win_idx,
    const int* __restrict__ rel_idx,
    const float* __restrict__ wqkvT,   // [96][32]
    const float* __restrict__ bqkv,
    const float* __restrict__ wprojT,  // [32][32] row = c_out
    const float* __restrict__ bproj,
    const u16* __restrict__ tqb, const u16* __restrict__ tkb, const u16* __restrict__ tvb, // [144][32] bf16
    float* __restrict__ out)
{
    __shared__ float xw[CAP][CC + 1];
    __shared__ float qs[CAP][CC + 1];
    __shared__ float ks2[CAP][CC + 1];
    __shared__ float vs[CAP][CC + 1];
    __shared__ float sc[NH][CAP][CAP + 1];
    __shared__ int ridx[CAP * CAP];
    __shared__ int widx[CAP];
    float (*ot)[CC + 1] = qs;  // qs dead after scores phase

    int w = blockIdx.x, t = threadIdx.x;
    if (t < CAP) widx[t] = win_idx[w * CAP + t];
    __syncthreads();

    for (int e = t; e < CAP * CC; e += 256) {
        int i = e >> 5, c = e & 31;
        xw[i][c] = x[(long)widx[i] * CC + c];
        ridx[e] = rel_idx[(long)w * CAP * CAP + e];
    }
    __syncthreads();

    // qkv projection: lanes share weight row tt (broadcast), i across lanes
    for (int o = t; o < CAP * 96; o += 256) {
        int i = o & 31, tt = o >> 5;
        float s = bqkv[tt];
        const float4* wr = (const float4*)(wqkvT + tt * 32);
#pragma unroll
        for (int q4 = 0; q4 < 8; q4++) {
            float4 wv = wr[q4];
            s = fmaf(xw[i][q4 * 4 + 0], wv.x, s);
            s = fmaf(xw[i][q4 * 4 + 1], wv.y, s);
            s = fmaf(xw[i][q4 * 4 + 2], wv.z, s);
            s = fmaf(xw[i][q4 * 4 + 3], wv.w, s);
        }
        int trip = tt >> 5, hd = tt & 31;
        if (trip == 0)      qs[i][hd] = s * 0.25f;   // HD^-0.5
        else if (trip == 1) ks2[i][hd] = s;
        else                vs[i][hd] = s;
    }
    __syncthreads();

    // scores + rel bias (bf16 tables, vector gathers)
    for (int e = t; e < NH * CAP * CAP; e += 256) {
        int h = e >> 10, i = (e >> 5) & 31, j = e & 31;
        int r = ridx[i * CAP + j];
        const float* qrow = &qs[i][h * HD];
        const float* krow = &ks2[j][h * HD];
        const uint2* tqp = (const uint2*)(tqb + r * CC + h * HD);
        const uint2* tkp = (const uint2*)(tkb + r * CC + h * HD);
        float s = 0.f;
#pragma unroll
        for (int w4 = 0; w4 < 4; w4++) {
            uint2 ua = tqp[w4], ub = tkp[w4];
            float tq0 = __uint_as_float(ua.x << 16), tq1 = __uint_as_float(ua.x & 0xffff0000u);
            float tq2 = __uint_as_float(ua.y << 16), tq3 = __uint_as_float(ua.y & 0xffff0000u);
            float tk0 = __uint_as_float(ub.x << 16), tk1 = __uint_as_float(ub.x & 0xffff0000u);
            float tk2 = __uint_as_float(ub.y << 16), tk3 = __uint_as_float(ub.y & 0xffff0000u);
            float q0 = qrow[w4 * 4 + 0], q1 = qrow[w4 * 4 + 1];
            float q2 = qrow[w4 * 4 + 2], q3 = qrow[w4 * 4 + 3];
            float k0 = krow[w4 * 4 + 0], k1 = krow[w4 * 4 + 1];
            float k2 = krow[w4 * 4 + 2], k3 = krow[w4 * 4 + 3];
            s = fmaf(q0, k0, s); s = fmaf(q0, tq0, s); s = fmaf(k0, tk0, s);
            s = fmaf(q1, k1, s); s = fmaf(q1, tq1, s); s = fmaf(k1, tk1, s);
            s = fmaf(q2, k2, s); s = fmaf(q2, tq2, s); s = fmaf(k2, tk2, s);
            s = fmaf(q3, k3, s); s = fmaf(q3, tq3, s); s = fmaf(k3, tk3, s);
        }
        sc[h][i][j] = s;
    }
    __syncthreads();

    // parallel softmax: 4 lanes per row, shfl_xor reduce
    {
        int rr = t >> 2, sub = t & 3;
        int h = rr >> 5, i = rr & 31, j0 = sub * 8;
        float pv[8];
        float m = -1e30f;
#pragma unroll
        for (int jj = 0; jj < 8; jj++) { pv[jj] = sc[h][i][j0 + jj]; m = fmaxf(m, pv[jj]); }
        m = fmaxf(m, __shfl_xor(m, 1));
        m = fmaxf(m, __shfl_xor(m, 2));
        float sum = 0.f;
#pragma unroll
        for (int jj = 0; jj < 8; jj++) { pv[jj] = __expf(pv[jj] - m); sum += pv[jj]; }
        sum += __shfl_xor(sum, 1);
        sum += __shfl_xor(sum, 2);
        float inv = 1.f / sum;
#pragma unroll
        for (int jj = 0; jj < 8; jj++) sc[h][i][j0 + jj] = pv[jj] * inv;
    }
    __syncthreads();

    // out = attn @ (v + tv[rel])
    for (int o = t; o < CAP * CC; o += 256) {
        int i = o >> 5, hd = o & 31, h = hd >> 4;
        float acc = 0.f;
#pragma unroll 8
        for (int j = 0; j < CAP; j++) {
            int r = ridx[i * CAP + j];
            float p = sc[h][i][j];
            float tvv = bf2f(tvb[r * CC + hd]);
            acc = fmaf(p, vs[j][hd] + tvv, acc);
        }
        ot[i][hd] = acc;
    }
    __syncthreads();

    // proj + residual scatter: lanes share wproj row c (broadcast)
    for (int o = t; o < CAP * CC; o += 256) {
        int i = o & 31, c = o >> 5;
        float s = bproj[c];
        const float4* wr = (const float4*)(wprojT + c * 32);
#pragma unroll
        for (int q4 = 0; q4 < 8; q4++) {
            float4 wv = wr[q4];
            s = fmaf(ot[i][q4 * 4 + 0], wv.x, s);
            s = fmaf(ot[i][q4 * 4 + 1], wv.y, s);
            s = fmaf(ot[i][q4 * 4 + 2], wv.z, s);
            s = fmaf(ot[i][q4 * 4 + 3], wv.w, s);
        }
        out[(long)widx[i] * CC + c] = xw[i][c] + s;
    }
}

// ---- ws byte offsets ----
#define B_FLAG   529408
#define B_ACTA   529920
#define B_ACTB   4724224
#define B_FEATS  8918528
#define B_WA1    9442816
#define B_WA2    9498112
#define B_WB1    9553408
#define B_WB2    9608704
#define B_WIN    9664000
#define B_WQKVT  9672192
#define B_WPROJT 9684480
#define B_TQB    9688576
#define B_TKB    9697792
#define B_TVB    9707008

extern "C" void kernel_launch(void* const* d_in, const int* in_sizes, int n_in,
                              void* d_out, int out_size, void* d_ws, size_t ws_size,
                              hipStream_t stream) {
    const void* feats  = d_in[0];
    const int* pairs   = (const int*)d_in[1];
    const int* win_idx = (const int*)d_in[2];
    const int* rel_idx = (const int*)d_in[3];

    char* wsb = (char*)d_ws;
    float* P  = (float*)wsb;
    int* flag = (int*)(wsb + B_FLAG);
    u16* actA = (u16*)(wsb + B_ACTA);
    u16* actB = (u16*)(wsb + B_ACTB);
    u16* fbf  = (u16*)(wsb + B_FEATS);
    u16* WpA1 = (u16*)(wsb + B_WA1);
    u16* WpA2 = (u16*)(wsb + B_WA2);
    u16* WpB1 = (u16*)(wsb + B_WB1);
    u16* WpB2 = (u16*)(wsb + B_WB2);
    u16* WpIN = (u16*)(wsb + B_WIN);
    float* wqkvT  = (float*)(wsb + B_WQKVT);
    float* wprojT = (float*)(wsb + B_WPROJT);
    u16* tqb = (u16*)(wsb + B_TQB);
    u16* tkb = (u16*)(wsb + B_TKB);
    u16* tvb = (u16*)(wsb + B_TVB);
    float* X  = (float*)d_out;

    detect_kernel<<<1, 256, 0, stream>>>((const u32*)feats, flag);

    PrepArgs pa;
    int si = 0;
    auto add = [&](int ii, int off, int n) {
        pa.s[si].src = d_in[ii]; pa.s[si].dst = off; pa.s[si].n = n; si++;
    };
    add(4,  OFF_WIN,   3456);
    add(7,  OFF_W1A,   27648);
    add(10, OFF_W2A,   27648);
    add(13, OFF_W1B,   27648);
    add(16, OFF_W2B,   27648);
    add(5,  OFF_GB + 0,   32);
    add(6,  OFF_GB + 32,  32);
    add(8,  OFF_GB + 64,  32);
    add(9,  OFF_GB + 96,  32);
    add(11, OFF_GB + 128, 32);
    add(12, OFF_GB + 160, 32);
    add(14, OFF_GB + 192, 32);
    add(15, OFF_GB + 224, 32);
    add(17, OFF_WQKV,  3072);
    add(18, OFF_BQKV,  96);
    add(19, OFF_WPROJ, 1024);
    add(20, OFF_BPROJ, 32);
    add(21, OFF_TQ,    4608);
    add(22, OFF_TK,    4608);
    add(23, OFF_TV,    4608);
    prep_kernel<<<dim3(108, 20), 256, 0, stream>>>(pa, P, flag);

    prep2_kernel<<<dim3(1024, 8), 256, 0, stream>>>(feats, flag, P, fbf,
                                                    WpA1, WpA2, WpB1, WpB2, WpIN,
                                                    wqkvT, wprojT, tqb, tkb, tvb);

    // x-chain lives in d_out; act ping-pongs in ws
    convin_mfma<<<1024, 256, 0, stream>>>(fbf, pairs, WpIN, P + OFF_GB + 0, X, actA);
    conv32_mfma<4><<<1024, 256, 0, stream>>>(actA, pairs, WpA1, P + OFF_GB + 64,  X, actB);
    conv32_mfma<7><<<1024, 256, 0, stream>>>(actB, pairs, WpA2, P + OFF_GB + 128, X, actA);
    conv32_mfma<4><<<1024, 256, 0, stream>>>(actA, pairs, WpB1, P + OFF_GB + 192, X, actB);
    conv32_mfma<3><<<1024, 256, 0, stream>>>(actB, pairs, WpB2, P, X, actA);

    attn2_kernel<<<NWIN, 256, 0, stream>>>(X, win_idx, rel_idx,
                                           wqkvT, P + OFF_BQKV, wprojT, P + OFF_BPROJ,
                                           tqb, tkb, tvb, X);
}

// Round 6
// 136.192 us; speedup vs baseline: 12.4338x; 1.2903x over previous
//
#include <hip/hip_runtime.h>

typedef unsigned short u16;
typedef unsigned int u32;

#define N_PTS 65536
#define KK 27
#define CIN 4
#define CC 32
#define NWIN 2048
#define CAP 32
#define NH 2
#define HD 16

typedef short s16x8 __attribute__((ext_vector_type(8)));
typedef float f32x4 __attribute__((ext_vector_type(4)));

__device__ __forceinline__ float bf2f(u16 h) { return __uint_as_float(((u32)h) << 16); }
__device__ __forceinline__ u16 f2bf(float f) {
    u32 u = __float_as_uint(f);
    u32 r = (u + 0x7FFFu + ((u >> 16) & 1u)) >> 16;
    return (u16)r;
}
__device__ __forceinline__ float ldany(const void* src, int i, bool isbf) {
    return isbf ? bf2f(((const u16*)src)[i]) : ((const float*)src)[i];
}
__device__ __forceinline__ u16 ldbf(const void* src, int i, bool isbf) {
    return isbf ? ((const u16*)src)[i] : f2bf(((const float*)src)[i]);
}
__device__ __forceinline__ void unp8(uint4 u, float* f) {
    f[0] = __uint_as_float(u.x << 16); f[1] = __uint_as_float(u.x & 0xffff0000u);
    f[2] = __uint_as_float(u.y << 16); f[3] = __uint_as_float(u.y & 0xffff0000u);
    f[4] = __uint_as_float(u.z << 16); f[5] = __uint_as_float(u.z & 0xffff0000u);
    f[6] = __uint_as_float(u.w << 16); f[7] = __uint_as_float(u.w & 0xffff0000u);
}

// ---- input float-dtype detection ----
__global__ void detect_kernel(const u32* __restrict__ w, int* flag) {
    int t = threadIdx.x;
    int cnt = 0;
    for (int i = t; i < 4096; i += 256) {
        u32 e = (w[i] >> 7) & 0xFFu;
        cnt += (e >= 100 && e <= 140) ? 1 : 0;
    }
    __shared__ int red[256];
    red[t] = cnt;
    __syncthreads();
    for (int s = 128; s > 0; s >>= 1) {
        if (t < s) red[t] += red[t + s];
        __syncthreads();
    }
    if (t == 0) flag[0] = (red[0] > 2048) ? 1 : 0;
}

// ---- single prep kernel: reads d_in directly (dtype-branch) ----
struct Ptrs { const void* p[24]; };

__global__ __launch_bounds__(256) void prep_all(
    Ptrs in, const int* __restrict__ flag,
    u16* __restrict__ fbf,
    u16* __restrict__ WpA1, u16* __restrict__ WpA2,
    u16* __restrict__ WpB1, u16* __restrict__ WpB2, u16* __restrict__ WpIN,
    u16* __restrict__ wqkvB, u16* __restrict__ wprojB,
    u16* __restrict__ tqb, u16* __restrict__ tkb, u16* __restrict__ tvb,
    float* __restrict__ Pf)
{
    bool isbf = flag[0] != 0;
    int seg = blockIdx.y;
    int i = blockIdx.x * 256 + threadIdx.x;
    if (seg == 0) {
        if (i < N_PTS * CIN) fbf[i] = ldbf(in.p[0], i, isbf);
        return;
    }
    if (seg <= 4) {
        if (i < 27648) {
            int e = i & 7, l = (i >> 3) & 63, dt = (i >> 9) & 1, k = i >> 10;
            const void* src = in.p[seg == 1 ? 7 : seg == 2 ? 10 : seg == 3 ? 13 : 16];
            u16* dst = seg == 1 ? WpA1 : seg == 2 ? WpA2 : seg == 3 ? WpB1 : WpB2;
            dst[i] = ldbf(src, k * 1024 + ((l >> 4) * 8 + e) * 32 + dt * 16 + (l & 15), isbf);
        }
        return;
    }
    if (seg == 5) {
        if (i < 4096) {
            int e = i & 7, l = (i >> 3) & 63, dt = (i >> 9) & 1, kk = i >> 10;
            int g = kk * 32 + (l >> 4) * 8 + e;
            int tp = g >> 2, c = g & 3;
            WpIN[i] = (tp < KK) ? ldbf(in.p[4], tp * 128 + c * 32 + dt * 16 + (l & 15), isbf) : (u16)0;
        }
        return;
    }
    if (seg == 6) {
        if (i < 3072) {
            int e = i & 7, l = (i >> 3) & 63, n = i >> 9;
            wqkvB[i] = ldbf(in.p[17], ((l >> 4) * 8 + e) * 96 + n * 16 + (l & 15), isbf);
        } else if (i < 4096) {
            int o2 = i - 3072;
            int e = o2 & 7, l = (o2 >> 3) & 63, n = o2 >> 9;
            wprojB[o2] = ldbf(in.p[19], ((l >> 4) * 8 + e) * 32 + n * 16 + (l & 15), isbf);
        }
        return;
    }
    if (seg == 7) {
        if (i < 4608)            tqb[i] = ldbf(in.p[21], i, isbf);
        else if (i < 9216)       tkb[i - 4608] = ldbf(in.p[22], i - 4608, isbf);
        else if (i < 13824)      tvb[i - 9216] = ldbf(in.p[23], i - 9216, isbf);
        return;
    }
    // seg 8: small fp32 params: GB(8x32) | bqkv(96)@256 | bproj(32)@352
    if (i < 256) {
        const int srcs[8] = {5, 6, 8, 9, 11, 12, 14, 15};
        Pf[i] = ldany(in.p[srcs[i >> 5]], i & 31, isbf);
    } else if (i < 352) {
        Pf[i] = ldany(in.p[18], i - 256, isbf);
    } else if (i < 384) {
        Pf[i] = ldany(in.p[20], i - 352, isbf);
    }
}

// ---- MFMA input conv: feats[N,4]bf16, taps packed 4-wide into K=128 ----
__global__ __launch_bounds__(256) void convin_mfma(
    const u16* __restrict__ fb, const int* __restrict__ pairs,
    const u16* __restrict__ Wp, const float* __restrict__ gb,
    float* __restrict__ xbuf, u16* __restrict__ act_out)
{
    int t = threadIdx.x;
    int wv = t >> 6, l = t & 63;
    int lr = l & 15, lg = l >> 4;
    int p0 = (blockIdx.x * 4 + wv) * 16;
    int rowaddr = p0 + lr;

    f32x4 acc0 = {0.f, 0.f, 0.f, 0.f}, acc1 = {0.f, 0.f, 0.f, 0.f};
#pragma unroll
    for (int kk = 0; kk < 4; kk++) {
        int t0 = kk * 8 + lg * 2;
        int ta = t0 < 26 ? t0 : 26;
        int tb = (t0 + 1) < 26 ? (t0 + 1) : 26;
        int ia = pairs[ta * N_PTS + rowaddr];
        int ib = pairs[tb * N_PTS + rowaddr];
        u32 ma = (t0 < KK && ia >= 0) ? 0xFFFFFFFFu : 0u;
        u32 mb = (t0 + 1 < KK && ib >= 0) ? 0xFFFFFFFFu : 0u;
        uint2 qa = *(const uint2*)(fb + (long)(ia < 0 ? 0 : ia) * CIN);
        uint2 qb = *(const uint2*)(fb + (long)(ib < 0 ? 0 : ib) * CIN);
        union { uint4 q; s16x8 v; } a;
        a.q = make_uint4(qa.x & ma, qa.y & ma, qb.x & mb, qb.y & mb);
        const s16x8* wb = (const s16x8*)Wp + kk * 128 + l;
        s16x8 b0 = wb[0];
        s16x8 b1 = wb[64];
        acc0 = __builtin_amdgcn_mfma_f32_16x16x32_bf16(a.v, b0, acc0, 0, 0, 0);
        acc1 = __builtin_amdgcn_mfma_f32_16x16x32_bf16(a.v, b1, acc1, 0, 0, 0);
    }
    float g0 = gb[lr], b0v = gb[32 + lr], g1 = gb[16 + lr], b1v = gb[48 + lr];
#pragma unroll
    for (int r = 0; r < 4; r++) {
        int row = p0 + lg * 4 + r;
        long o0 = (long)row * 32 + lr, o1 = o0 + 16;
        float v0 = acc0[r], v1 = acc1[r];
        xbuf[o0] = v0; xbuf[o1] = v1;
        act_out[o0] = f2bf(fmaxf(fmaf(v0, g0, b0v), 0.f));
        act_out[o1] = f2bf(fmaxf(fmaf(v1, g1, b1v), 0.f));
    }
}

// ---- MFMA 32->32 gather conv; full unroll + index prefetch ----
// M: bit0 READ_X, bit1 WRITE_X, bit2 WRITE_ACT
template <int M>
__global__ __launch_bounds__(256) void conv32_mfma(
    const u16* __restrict__ act_in, const int* __restrict__ pairs,
    const u16* __restrict__ Wp, const float* __restrict__ gb,
    float* __restrict__ xbuf, u16* __restrict__ act_out)
{
    int t = threadIdx.x;
    int wv = t >> 6, l = t & 63;
    int lr = l & 15, lg = l >> 4;
    int p0 = (blockIdx.x * 4 + wv) * 16;
    int rowaddr = p0 + lr;

    int idx[KK];
#pragma unroll
    for (int k = 0; k < KK; k++) idx[k] = pairs[k * N_PTS + rowaddr];

    f32x4 acc0 = {0.f, 0.f, 0.f, 0.f}, acc1 = {0.f, 0.f, 0.f, 0.f};
#pragma unroll
    for (int k = 0; k < KK; k++) {
        const s16x8* wb = (const s16x8*)Wp + k * 128 + l;
        s16x8 b0 = wb[0];
        s16x8 b1 = wb[64];
        int ic = idx[k] < 0 ? 0 : idx[k];
        uint4 q = *(const uint4*)(act_in + (long)ic * CC + lg * 8);
        u32 msk = idx[k] >= 0 ? 0xFFFFFFFFu : 0u;
        q.x &= msk; q.y &= msk; q.z &= msk; q.w &= msk;
        union { uint4 q; s16x8 v; } a;
        a.q = q;
        acc0 = __builtin_amdgcn_mfma_f32_16x16x32_bf16(a.v, b0, acc0, 0, 0, 0);
        acc1 = __builtin_amdgcn_mfma_f32_16x16x32_bf16(a.v, b1, acc1, 0, 0, 0);
    }
    float g0 = 0.f, b0v = 0.f, g1 = 0.f, b1v = 0.f;
    if (M & 4) { g0 = gb[lr]; b0v = gb[32 + lr]; g1 = gb[16 + lr]; b1v = gb[48 + lr]; }
#pragma unroll
    for (int r = 0; r < 4; r++) {
        int row = p0 + lg * 4 + r;
        long o0 = (long)row * 32 + lr, o1 = o0 + 16;
        float v0 = acc0[r], v1 = acc1[r];
        if (M & 1) { v0 += xbuf[o0]; v1 += xbuf[o1]; }
        if (M & 2) { xbuf[o0] = v0; xbuf[o1] = v1; }
        if (M & 4) {
            act_out[o0] = f2bf(fmaxf(fmaf(v0, g0, b0v), 0.f));
            act_out[o1] = f2bf(fmaxf(fmaf(v1, g1, b1v), 0.f));
        }
    }
}

// ---- fused windowed attention v3: MFMA for qkv / qk^T / PV / proj ----
__global__ __launch_bounds__(256) void attn3_kernel(
    const float* __restrict__ x, const int* __restrict__ win_idx,
    const int* __restrict__ rel_idx,
    const u16* __restrict__ wqkvB, const u16* __restrict__ wprojB,
    const float* __restrict__ Pf,    // bqkv@256, bproj@352
    const u16* __restrict__ tqb, const u16* __restrict__ tkb, const u16* __restrict__ tvb,
    float* __restrict__ out)
{
    __shared__ float xw[CAP][CC + 1];
    __shared__ u16 qsb[CAP][40];
    __shared__ u16 ksb[CAP][40];
    __shared__ u16 vsT[CC][40];
    __shared__ float sc[NH][CAP][36];
    __shared__ float ot[CAP][36];
    __shared__ int ridx[CAP * CAP];
    __shared__ int widx[CAP];

    int w = blockIdx.x, t = threadIdx.x;
    int wv = t >> 6, l = t & 63, lr = l & 15, lg = l >> 4;

    if (t < CAP) widx[t] = win_idx[w * CAP + t];
    __syncthreads();

    for (int e = t; e < CAP * CC; e += 256) {
        int i = e >> 5, c = e & 31;
        xw[i][c] = x[(long)widx[i] * CC + c];
        ridx[e] = rel_idx[(long)w * CAP * CAP + e];
    }
    __syncthreads();

    // ---- qkv: 12 MFMA (2 m-tiles x 6 out-tiles), K=32 ----
    {
        const float* bqkv = Pf + 256;
        for (int pi = wv; pi < 12; pi += 4) {
            int n = pi >> 1, m = pi & 1;
            union { s16x8 v; u16 h[8]; } a;
            const float* xr = &xw[m * 16 + lr][0];
#pragma unroll
            for (int e = 0; e < 8; e++) a.h[e] = f2bf(xr[lg * 8 + e]);
            s16x8 b = *(const s16x8*)(wqkvB + ((n * 64 + l) << 3));
            f32x4 acc = {0.f, 0.f, 0.f, 0.f};
            acc = __builtin_amdgcn_mfma_f32_16x16x32_bf16(a.v, b, acc, 0, 0, 0);
            int tt = n * 16 + lr;
            float bias = bqkv[tt];
#pragma unroll
            for (int r = 0; r < 4; r++) {
                int tok = m * 16 + lg * 4 + r;
                float v = acc[r] + bias;
                if (tt < 32)      qsb[tok][tt] = f2bf(v * 0.25f);     // HD^-0.5
                else if (tt < 64) ksb[tok][tt - 32] = f2bf(v);
                else              vsT[tt - 64][tok] = f2bf(v);
            }
        }
    }
    __syncthreads();

    // ---- qk^T: 8 MFMA (h, m-tile, j-tile); K upper half zero-padded ----
    for (int pi = wv; pi < 8; pi += 4) {
        int h = pi >> 2, m = (pi >> 1) & 1, n = pi & 1;
        s16x8 a = {0, 0, 0, 0, 0, 0, 0, 0}, b = {0, 0, 0, 0, 0, 0, 0, 0};
        if (lg < 2) {
            a = *(const s16x8*)(&qsb[m * 16 + lr][h * 16 + lg * 8]);
            b = *(const s16x8*)(&ksb[n * 16 + lr][h * 16 + lg * 8]);
        }
        f32x4 acc = {0.f, 0.f, 0.f, 0.f};
        acc = __builtin_amdgcn_mfma_f32_16x16x32_bf16(a, b, acc, 0, 0, 0);
#pragma unroll
        for (int r = 0; r < 4; r++)
            sc[h][m * 16 + lg * 4 + r][n * 16 + lr] = acc[r];
    }
    __syncthreads();

    // ---- rel-bias gathers: sc += q.tq[r] + k.tk[r] ----
    for (int e = t; e < NH * CAP * CAP; e += 256) {
        int h = e >> 10, i = (e >> 5) & 31, j = e & 31;
        int r = ridx[i * 32 + j];
        float qf[16], kf[16], tf[16], uf[16];
        unp8(*(const uint4*)(&qsb[i][h * 16]), qf);
        unp8(*(const uint4*)(&qsb[i][h * 16 + 8]), qf + 8);
        unp8(*(const uint4*)(&ksb[j][h * 16]), kf);
        unp8(*(const uint4*)(&ksb[j][h * 16 + 8]), kf + 8);
        unp8(*(const uint4*)(tqb + r * 32 + h * 16), tf);
        unp8(*(const uint4*)(tqb + r * 32 + h * 16 + 8), tf + 8);
        unp8(*(const uint4*)(tkb + r * 32 + h * 16), uf);
        unp8(*(const uint4*)(tkb + r * 32 + h * 16 + 8), uf + 8);
        float s = sc[h][i][j];
#pragma unroll
        for (int d = 0; d < 16; d++) {
            s = fmaf(qf[d], tf[d], s);
            s = fmaf(kf[d], uf[d], s);
        }
        sc[h][i][j] = s;
    }
    __syncthreads();

    // ---- softmax: 4 lanes per row ----
    {
        int rr = t >> 2, sub = t & 3;
        int h = rr >> 5, i = rr & 31, j0 = sub * 8;
        float pv[8];
        float m = -1e30f;
#pragma unroll
        for (int jj = 0; jj < 8; jj++) { pv[jj] = sc[h][i][j0 + jj]; m = fmaxf(m, pv[jj]); }
        m = fmaxf(m, __shfl_xor(m, 1));
        m = fmaxf(m, __shfl_xor(m, 2));
        float sum = 0.f;
#pragma unroll
        for (int jj = 0; jj < 8; jj++) { pv[jj] = __expf(pv[jj] - m); sum += pv[jj]; }
        sum += __shfl_xor(sum, 1);
        sum += __shfl_xor(sum, 2);
        float inv = 1.f / sum;
#pragma unroll
        for (int jj = 0; jj < 8; jj++) sc[h][i][j0 + jj] = pv[jj] * inv;
    }
    __syncthreads();

    // ---- tv gather part: ot = sum_j p * tv[r], 2 channels per lane ----
    for (int o = t; o < CAP * 16; o += 256) {
        int i = o >> 4, hp = o & 15;
        int h = hp >> 3;
        float a0 = 0.f, a1 = 0.f;
#pragma unroll 8
        for (int j = 0; j < CAP; j++) {
            int r = ridx[i * 32 + j];
            float p = sc[h][i][j];
            u32 tv2 = *(const u32*)(tvb + r * 32 + hp * 2);
            a0 = fmaf(p, __uint_as_float(tv2 << 16), a0);
            a1 = fmaf(p, __uint_as_float(tv2 & 0xffff0000u), a1);
        }
        ot[i][hp * 2] = a0;
        ot[i][hp * 2 + 1] = a1;
    }
    __syncthreads();

    // ---- PV: 4 MFMA (h, m-tile), K=32 over j ----
    {
        int h = wv >> 1, m = wv & 1;
        union { s16x8 v; u16 hh[8]; } pa;
        const float* pr = &sc[h][m * 16 + lr][0];
#pragma unroll
        for (int e = 0; e < 8; e++) pa.hh[e] = f2bf(pr[lg * 8 + e]);
        s16x8 b = *(const s16x8*)(&vsT[h * 16 + lr][lg * 8]);
        f32x4 acc = {0.f, 0.f, 0.f, 0.f};
        acc = __builtin_amdgcn_mfma_f32_16x16x32_bf16(pa.v, b, acc, 0, 0, 0);
#pragma unroll
        for (int r = 0; r < 4; r++)
            ot[m * 16 + lg * 4 + r][h * 16 + lr] += acc[r];
    }
    __syncthreads();

    // ---- proj: 4 MFMA + residual scatter ----
    {
        int m = wv >> 1, n = wv & 1;
        union { s16x8 v; u16 hh[8]; } a;
        const float* orow = &ot[m * 16 + lr][0];
#pragma unroll
        for (int e = 0; e < 8; e++) a.hh[e] = f2bf(orow[lg * 8 + e]);
        s16x8 b = *(const s16x8*)(wprojB + ((n * 64 + l) << 3));
        f32x4 acc = {0.f, 0.f, 0.f, 0.f};
        acc = __builtin_amdgcn_mfma_f32_16x16x32_bf16(a.v, b, acc, 0, 0, 0);
        int c = n * 16 + lr;
        float bb = Pf[352 + c];
#pragma unroll
        for (int r = 0; r < 4; r++) {
            int tok = m * 16 + lg * 4 + r;
            out[(long)widx[tok] * CC + c] = xw[tok][c] + bb + acc[r];
        }
    }
}

// ---- ws byte offsets ----
#define B_PF     0          // 384 floats
#define B_FLAG   1536
#define B_ACTA   2048
#define B_ACTB   4196352
#define B_FEATS  8390656
#define B_WA1    8914944
#define B_WA2    8970240
#define B_WB1    9025536
#define B_WB2    9080832
#define B_WIN    9136128
#define B_WQKVB  9144320
#define B_WPROJB 9150464
#define B_TQB    9152512
#define B_TKB    9161728
#define B_TVB    9170944

extern "C" void kernel_launch(void* const* d_in, const int* in_sizes, int n_in,
                              void* d_out, int out_size, void* d_ws, size_t ws_size,
                              hipStream_t stream) {
    const void* feats  = d_in[0];
    const int* pairs   = (const int*)d_in[1];
    const int* win_idx = (const int*)d_in[2];
    const int* rel_idx = (const int*)d_in[3];

    char* wsb = (char*)d_ws;
    float* Pf = (float*)(wsb + B_PF);
    int* flag = (int*)(wsb + B_FLAG);
    u16* actA = (u16*)(wsb + B_ACTA);
    u16* actB = (u16*)(wsb + B_ACTB);
    u16* fbf  = (u16*)(wsb + B_FEATS);
    u16* WpA1 = (u16*)(wsb + B_WA1);
    u16* WpA2 = (u16*)(wsb + B_WA2);
    u16* WpB1 = (u16*)(wsb + B_WB1);
    u16* WpB2 = (u16*)(wsb + B_WB2);
    u16* WpIN = (u16*)(wsb + B_WIN);
    u16* wqkvB  = (u16*)(wsb + B_WQKVB);
    u16* wprojB = (u16*)(wsb + B_WPROJB);
    u16* tqb = (u16*)(wsb + B_TQB);
    u16* tkb = (u16*)(wsb + B_TKB);
    u16* tvb = (u16*)(wsb + B_TVB);
    float* X  = (float*)d_out;

    detect_kernel<<<1, 256, 0, stream>>>((const u32*)feats, flag);

    Ptrs pp;
    for (int i = 0; i < 24; i++) pp.p[i] = d_in[i];
    prep_all<<<dim3(1024, 9), 256, 0, stream>>>(pp, flag, fbf,
                                                WpA1, WpA2, WpB1, WpB2, WpIN,
                                                wqkvB, wprojB, tqb, tkb, tvb, Pf);

    convin_mfma<<<1024, 256, 0, stream>>>(fbf, pairs, WpIN, Pf + 0, X, actA);
    conv32_mfma<4><<<1024, 256, 0, stream>>>(actA, pairs, WpA1, Pf + 64,  X, actB);
    conv32_mfma<7><<<1024, 256, 0, stream>>>(actB, pairs, WpA2, Pf + 128, X, actA);
    conv32_mfma<4><<<1024, 256, 0, stream>>>(actA, pairs, WpB1, Pf + 192, X, actB);
    conv32_mfma<3><<<1024, 256, 0, stream>>>(actB, pairs, WpB2, Pf, X, actA);

    attn3_kernel<<<NWIN, 256, 0, stream>>>(X, win_idx, rel_idx,
                                           wqkvB, wprojB, Pf,
                                           tqb, tkb, tvb, X);
}